// Round 11
// baseline (112.635 us; speedup 1.0000x reference)
//
#include <hip/hip_runtime.h>
#include <hip/hip_bf16.h>

// ---------- types ----------
typedef __attribute__((ext_vector_type(8))) short s16x8;   // 8 x bf16 (4 VGPR)
typedef __attribute__((ext_vector_type(4))) float f32x4;   // MFMA acc

#define B_SZ 64
#define T_SZ 2000
#define QD 1024
#define MD 512
#define AD 128
#define NF 32
#define KW 31
#define NTILE 63
#define ASTRIDE 1056   // Atile row stride BYTES (264 words == 8 mod 32 banks)
#define APSTRIDE 136   // A' row stride BYTES (34 words: 2-way banks, free)

// ---------- helpers ----------
__device__ __forceinline__ unsigned short f2bf(float f) {
    unsigned int u = __float_as_uint(f);
    unsigned int r = (u + 0x7FFFu + ((u >> 16) & 1u)) >> 16;  // RNE
    return (unsigned short)r;
}
__device__ __forceinline__ unsigned int pack2bf(float a, float b) {
    union { __hip_bfloat162 h; unsigned int u; } cv;
    cv.h = __float22bfloat162_rn(float2{a, b});
    return cv.u;
}
__device__ __forceinline__ float fast_tanh(float x) {
    float ax = fabsf(x);
    float e = __expf(2.0f * ax);
    float r = 1.0f - 2.0f * __builtin_amdgcn_rcpf(e + 1.0f);
    return x < 0.0f ? -r : r;
}

// ---------- kernel A: pq + WB pack + W2 = Wconv@Wl pack ----------
// blocks 0..63: pq; 64..79: WB; 80: W2B
__global__ __launch_bounds__(512) void prep_kernel(
    const float* __restrict__ ahs, const float* __restrict__ Wq,
    const float* __restrict__ Wm, const float* __restrict__ Wconv,
    const float* __restrict__ Wl, float* __restrict__ pq,
    unsigned short* __restrict__ WB, unsigned short* __restrict__ W2B) {
    const int blk = blockIdx.x, tid = threadIdx.x;
    if (blk < 64) {
        __shared__ float q_sm[QD];
        __shared__ float part[3][AD];
        ((float2*)q_sm)[tid] = ((const float2*)(ahs + blk * QD))[tid];
        __syncthreads();
        const int d = tid & 127, kh = tid >> 7;
        const int k0 = kh * 256;
        float a0 = 0, a1 = 0, a2 = 0, a3 = 0;
        #pragma unroll 4
        for (int k = k0; k < k0 + 256; k += 4) {
            a0 += q_sm[k]     * Wq[(k)     * AD + d];
            a1 += q_sm[k + 1] * Wq[(k + 1) * AD + d];
            a2 += q_sm[k + 2] * Wq[(k + 2) * AD + d];
            a3 += q_sm[k + 3] * Wq[(k + 3) * AD + d];
        }
        float s = (a0 + a1) + (a2 + a3);
        if (kh) part[kh - 1][d] = s;
        __syncthreads();
        if (tid < AD)
            pq[blk * AD + tid] =
                fast_tanh((s + part[0][tid]) + (part[1][tid] + part[2][tid]));
    } else if (blk < 80) {
        int cidx = (blk - 64) * 512 + tid;        // 0..8191 = (n,s,l)
        int n = cidx >> 10, s = (cidx >> 6) & 15, l = cidx & 63;
        int col = n * 16 + (l & 15);
        int krow = s * 32 + (l >> 4) * 8;
        float v[8];
        #pragma unroll
        for (int j = 0; j < 8; ++j) v[j] = Wm[(krow + j) * AD + col];
        uint4 pk;
        pk.x = pack2bf(v[0], v[1]); pk.y = pack2bf(v[2], v[3]);
        pk.z = pack2bf(v[4], v[5]); pk.w = pack2bf(v[6], v[7]);
        *(uint4*)(WB + cidx * 8) = pk;
    } else {
        // W2[kc][d] = sum_f Wconv[k][c][f] * Wl[f][d],  kc = 2k+c (62 used, 2 pad)
        __shared__ float wl_sm[NF * AD];           // 16 KB
        for (int h = tid; h < NF * AD; h += 512) wl_sm[h] = Wl[h];
        __syncthreads();
        #pragma unroll
        for (int h = 0; h < 16; ++h) {
            int idx = h * 512 + tid;               // = (ns*64+l)*8+j
            int j = idx & 7, l = (idx >> 3) & 63, ns = idx >> 9;
            int s = ns & 1, n = ns >> 1;
            int lr = l & 15, lg = l >> 4;
            int kc = 32 * s + 8 * lg + j;
            int d = 16 * n + lr;
            float acc = 0.0f;
            if (kc < 62) {
                const float* wrow = Wconv + (kc >> 1) * 2 * NF + (kc & 1) * NF;
                #pragma unroll 8
                for (int f = 0; f < NF; ++f) acc += wrow[f] * wl_sm[f * AD + d];
            }
            W2B[idx] = f2bf(acc);
        }
    }
}

// ---------- kernel B: pm + ploc(A'@W2) + p + ctx partials ----------
// grid (63, 64); block 256 (4 waves). TT=32. A'-build hidden under staged loads.
__global__ __launch_bounds__(256, 4) void energy_kernel(
    const float* __restrict__ memory, const float* __restrict__ awcat,
    const float* __restrict__ Wv, const float* __restrict__ pq,
    const unsigned short* __restrict__ WB, const unsigned short* __restrict__ W2B,
    float* __restrict__ wts, float* __restrict__ ctile,
    float* __restrict__ mloc, float* __restrict__ Stile) {
    const int tile = blockIdx.x;
    const int b = blockIdx.y;
    const int t0 = tile * 32;
    const int tid = threadIdx.x;

    __shared__ __align__(16) unsigned short Atile[32 * (ASTRIDE / 2)]; // 33 KB
    __shared__ float aw2[64][2];                                       // 0.5 KB
    __shared__ __align__(16) unsigned short Aploc[32 * (APSTRIDE / 2)]; // 4.35 KB
    __shared__ float e_part[32][4];
    __shared__ float p_sm[32];

    // 1: awc loads issued FIRST (oldest in vmcnt queue -> completes early)
    float awv = 0.0f;
    if (tid < 128) {
        int c = tid >> 6, i = tid & 63;
        int tv = t0 - 15 + i;
        if (i < 63 && tv >= 0 && tv < T_SZ) awv = awcat[(b * 2 + c) * T_SZ + tv];
    }

    // 2: issue all 16 memory loads (stay in flight through A'-build)
    float4 v[16];
    {
        const float4* msrc = (const float4*)(memory + ((size_t)b * T_SZ + t0) * MD);
        #pragma unroll
        for (int it = 0; it < 8; ++it) {
            int cid = it * 256 + tid;
            int r = cid >> 6, cc = cid & 63;
            float4 z = {0, 0, 0, 0};
            bool ok = (t0 + r < T_SZ);
            v[2 * it]     = ok ? msrc[r * 128 + cc * 2]     : z;
            v[2 * it + 1] = ok ? msrc[r * 128 + cc * 2 + 1] : z;
        }
    }

    // 3: aw2 write (waits only the awc loads)
    if (tid < 128) aw2[tid & 63][tid >> 6] = awv;
    __syncthreads();

    // 4: build A' (LDS-only; memory loads still in flight)
    //    A'[t][2k+c] = awc[c][t0-15+t+k], zero for k=31
    {
        int row = tid >> 3, ch = tid & 7;
        uint4 pk;
        unsigned int* pw = (unsigned int*)&pk;
        #pragma unroll
        for (int jj = 0; jj < 4; ++jj) {
            int k = ch * 4 + jj;
            float2 x = (k < 31) ? *(const float2*)aw2[row + k] : float2{0.0f, 0.0f};
            pw[jj] = pack2bf(x.x, x.y);
        }
        *(uint4*)((char*)Aploc + row * APSTRIDE + ch * 16) = pk;
    }

    // 5: convert + write Atile (the only phase waiting on HBM)
    {
        #pragma unroll
        for (int it = 0; it < 8; ++it) {
            int cid = it * 256 + tid;
            int r = cid >> 6, cc = cid & 63;
            float4 v0 = v[2 * it], v1 = v[2 * it + 1];
            uint4 pk;
            pk.x = pack2bf(v0.x, v0.y); pk.y = pack2bf(v0.z, v0.w);
            pk.z = pack2bf(v1.x, v1.y); pk.w = pack2bf(v1.z, v1.w);
            int off = r * ASTRIDE + ((cc * 16) ^ ((r & 7) << 4));
            *(uint4*)((char*)Atile + off) = pk;
        }
    }
    __syncthreads();

    // 6: MFMA phase
    const int w = tid >> 6, l = tid & 63;
    const int lr = l & 15, lg = l >> 4;
    const int d0 = (2 * w + 0) * 16 + lr;
    const int d1 = (2 * w + 1) * 16 + lr;
    const float pqv0 = pq[b * AD + d0], pqv1 = pq[b * AD + d1];
    const float wvv0 = Wv[d0], wvv1 = Wv[d1];

    f32x4 zero4 = {0, 0, 0, 0};
    f32x4 p00 = zero4, p01 = zero4, p10 = zero4, p11 = zero4;

    const s16x8* wbp = (const s16x8*)WB;
    const int swz = (lr & 7) << 4;
    const int rbase0 = lr * ASTRIDE;
    const int rbase1 = (16 + lr) * ASTRIDE;
    const int inb = lg * 16;
    const char* Ac = (const char*)Atile;

    #pragma unroll
    for (int s = 0; s < 16; ++s) {
        int j = (inb + s * 64) ^ swz;
        s16x8 a0 = *(const s16x8*)(Ac + rbase0 + j);
        s16x8 a1 = *(const s16x8*)(Ac + rbase1 + j);
        s16x8 b0 = wbp[((2 * w + 0) * 16 + s) * 64 + l];
        s16x8 b1 = wbp[((2 * w + 1) * 16 + s) * 64 + l];
        p00 = __builtin_amdgcn_mfma_f32_16x16x32_bf16(a0, b0, p00, 0, 0, 0);
        p01 = __builtin_amdgcn_mfma_f32_16x16x32_bf16(a0, b1, p01, 0, 0, 0);
        p10 = __builtin_amdgcn_mfma_f32_16x16x32_bf16(a1, b0, p10, 0, 0, 0);
        p11 = __builtin_amdgcn_mfma_f32_16x16x32_bf16(a1, b1, p11, 0, 0, 0);
    }

    // ploc = A' @ W2 (K=64, 2 k-steps)
    f32x4 q00 = zero4, q01 = zero4, q10 = zero4, q11 = zero4;
    {
        const s16x8* w2p = (const s16x8*)W2B;
        const char* Apc = (const char*)Aploc;
        #pragma unroll
        for (int s = 0; s < 2; ++s) {
            s16x8 a0 = *(const s16x8*)(Apc + lr * APSTRIDE + inb + s * 64);
            s16x8 a1 = *(const s16x8*)(Apc + (16 + lr) * APSTRIDE + inb + s * 64);
            s16x8 b0 = w2p[(((2 * w + 0) * 2 + s) * 64) + l];
            s16x8 b1 = w2p[(((2 * w + 1) * 2 + s) * 64) + l];
            q00 = __builtin_amdgcn_mfma_f32_16x16x32_bf16(a0, b0, q00, 0, 0, 0);
            q01 = __builtin_amdgcn_mfma_f32_16x16x32_bf16(a0, b1, q01, 0, 0, 0);
            q10 = __builtin_amdgcn_mfma_f32_16x16x32_bf16(a1, b0, q10, 0, 0, 0);
            q11 = __builtin_amdgcn_mfma_f32_16x16x32_bf16(a1, b1, q11, 0, 0, 0);
        }
    }

    // epilogue: e[t] partial = sum_d tanh(pq + tanh(ploc) + tanh(pm)) * Wv
    float vr[8];
    #pragma unroll
    for (int r = 0; r < 4; ++r) {
        vr[r]     = fast_tanh(pqv0 + fast_tanh(q00[r]) + fast_tanh(p00[r])) * wvv0
                  + fast_tanh(pqv1 + fast_tanh(q01[r]) + fast_tanh(p01[r])) * wvv1;
        vr[4 + r] = fast_tanh(pqv0 + fast_tanh(q10[r]) + fast_tanh(p10[r])) * wvv0
                  + fast_tanh(pqv1 + fast_tanh(q11[r]) + fast_tanh(p11[r])) * wvv1;
    }
    #pragma unroll
    for (int j = 0; j < 8; ++j) {
        float vv = vr[j];
        vv += __shfl_xor(vv, 1);
        vv += __shfl_xor(vv, 2);
        vv += __shfl_xor(vv, 4);
        vv += __shfl_xor(vv, 8);
        if (lr == 0) e_part[(j >> 2) * 16 + lg * 4 + (j & 3)][w] = vv;
    }
    __syncthreads();

    if (tid < 32) {
        int t = t0 + tid;
        bool valid = t < T_SZ;
        float e = (e_part[tid][0] + e_part[tid][1]) + (e_part[tid][2] + e_part[tid][3]);
        float m = valid ? e : -3.4e38f;
        m = fmaxf(m, __shfl_xor(m, 1));
        m = fmaxf(m, __shfl_xor(m, 2));
        m = fmaxf(m, __shfl_xor(m, 4));
        m = fmaxf(m, __shfl_xor(m, 8));
        m = fmaxf(m, __shfl_xor(m, 16));
        float p = valid ? __expf(e - m) : 0.0f;
        p_sm[tid] = p;
        float S = p;
        S += __shfl_xor(S, 1);
        S += __shfl_xor(S, 2);
        S += __shfl_xor(S, 4);
        S += __shfl_xor(S, 8);
        S += __shfl_xor(S, 16);
        if (valid) wts[b * T_SZ + t] = p;
        if (tid == 0) { mloc[b * NTILE + tile] = m; Stile[b * NTILE + tile] = S; }
    }
    __syncthreads();

    // ctx partial: thread owns d = 2*tid, 2*tid+1
    {
        float c0 = 0.0f, c1 = 0.0f;
        const int boff = tid * 4;
        #pragma unroll
        for (int t = 0; t < 32; ++t) {
            float p = p_sm[t];
            unsigned int pk = *(const unsigned int*)(
                Ac + t * ASTRIDE + (boff ^ ((t & 7) << 4)));
            c0 += p * __uint_as_float(pk << 16);
            c1 += p * __uint_as_float(pk & 0xffff0000u);
        }
        float2 o; o.x = c0; o.y = c1;
        ((float2*)ctile)[((b * NTILE + tile) << 8) + tid] = o;
    }
}

// ---------- kernel C: finalize (global M,Z; rescale wts; reduce ctx) ----------
__global__ __launch_bounds__(256) void finalize_kernel(
    const float* __restrict__ mloc, const float* __restrict__ Stile,
    const float* __restrict__ ctile, float* __restrict__ wts,
    float* __restrict__ ctx) {
    const int b = blockIdx.x, h = blockIdx.y, tid = threadIdx.x;
    __shared__ float sc_sm[NTILE + 1];
    if (tid < 64) {
        float m = (tid < NTILE) ? mloc[b * NTILE + tid] : -3.4e38f;
        float s = (tid < NTILE) ? Stile[b * NTILE + tid] : 0.0f;
        float M = m;
        M = fmaxf(M, __shfl_xor(M, 1));  M = fmaxf(M, __shfl_xor(M, 2));
        M = fmaxf(M, __shfl_xor(M, 4));  M = fmaxf(M, __shfl_xor(M, 8));
        M = fmaxf(M, __shfl_xor(M, 16)); M = fmaxf(M, __shfl_xor(M, 32));
        float e = __expf(m - M);
        float z = e * s;
        z += __shfl_xor(z, 1);  z += __shfl_xor(z, 2);
        z += __shfl_xor(z, 4);  z += __shfl_xor(z, 8);
        z += __shfl_xor(z, 16); z += __shfl_xor(z, 32);
        if (tid < NTILE) sc_sm[tid] = e / z;
    }
    __syncthreads();

    if (h == 0) {
        #pragma unroll
        for (int i = 0; i < 8; ++i) {
            int idx = tid + i * 256;
            if (idx < T_SZ) wts[b * T_SZ + idx] *= sc_sm[idx >> 5];
        }
    }

    float a = 0.0f;
    const float* cb = ctile + ((size_t)b * NTILE << 9) + h * 256 + tid;
    #pragma unroll 7
    for (int tl = 0; tl < NTILE; ++tl) a += sc_sm[tl] * cb[(size_t)tl << 9];
    ctx[b * MD + h * 256 + tid] = a;
}

// ---------- launch ----------
extern "C" void kernel_launch(void* const* d_in, const int* in_sizes, int n_in,
                              void* d_out, int out_size, void* d_ws, size_t ws_size,
                              hipStream_t stream) {
    const float* ahs    = (const float*)d_in[0];
    const float* memory = (const float*)d_in[1];
    const float* awcat  = (const float*)d_in[2];
    const float* Wq     = (const float*)d_in[3];
    const float* Wm     = (const float*)d_in[4];
    const float* Wv     = (const float*)d_in[5];
    const float* Wconv  = (const float*)d_in[6];
    const float* Wl     = (const float*)d_in[7];

    float* out = (float*)d_out;
    float* ctx = out;                 // [64][512]
    float* wts = out + B_SZ * MD;     // [64][2000]

    char* ws = (char*)d_ws;
    float* pq             = (float*)(ws);                    // 32 KB
    unsigned short* WB    = (unsigned short*)(ws + 32768);   // 128 KB
    unsigned short* W2B   = (unsigned short*)(ws + 163840);  // 16 KB
    float* mloc           = (float*)(ws + 180224);           // 15.75 KB
    float* Stile          = (float*)(ws + 196608);           // 15.75 KB
    float* ctile          = (float*)(ws + 221184);           // 8.26 MB

    prep_kernel<<<81, 512, 0, stream>>>(ahs, Wq, Wm, Wconv, Wl, pq, WB, W2B);
    energy_kernel<<<dim3(NTILE, B_SZ), 256, 0, stream>>>(
        memory, awcat, Wv, pq, WB, W2B, wts, ctile, mloc, Stile);
    finalize_kernel<<<dim3(B_SZ, 2), 256, 0, stream>>>(mloc, Stile, ctile, wts, ctx);
}